// Round 2
// baseline (333.883 us; speedup 1.0000x reference)
//
#include <hip/hip_runtime.h>
#include <hip/hip_bf16.h>

typedef __hip_bfloat16 HBF;
typedef __bf16 bf16x8 __attribute__((ext_vector_type(8)));
typedef float f32x4 __attribute__((ext_vector_type(4)));
typedef float float4v __attribute__((ext_vector_type(4)));

__device__ __forceinline__ float toF(float x) { return x; }
__device__ __forceinline__ float toF(HBF x) { return __bfloat162float(x); }

#define MFMA16(a, b, c) __builtin_amdgcn_mfma_f32_16x16x32_bf16((a), (b), (c), 0, 0, 0)

// async global->LDS, 16B per lane. LDS dest must be wave-uniform base; HW adds lane*16.
__device__ __forceinline__ void gload_lds16(const HBF* g, HBF* l) {
  __builtin_amdgcn_global_load_lds((const __attribute__((address_space(1))) void*)g,
                                   (__attribute__((address_space(3))) void*)l, 16, 0, 0);
}

// ---------------- elementwise cast f32 -> bf16 (vectorized) ----------------
struct bf4 { HBF v[4]; };
__global__ void cast_f32_bf16_k(const float* __restrict__ in, HBF* __restrict__ out, int n4) {
  int i = blockIdx.x * 256 + threadIdx.x;
  if (i >= n4) return;
  float4v a = reinterpret_cast<const float4v*>(in)[i];
  bf4 o;
  o.v[0] = __float2bfloat16(a.x); o.v[1] = __float2bfloat16(a.y);
  o.v[2] = __float2bfloat16(a.z); o.v[3] = __float2bfloat16(a.w);
  reinterpret_cast<bf4*>(out)[i] = o;
}

// ---------------- batched tiled transpose-cast: (bt,R,C) Tin -> (bt,C,R) bf16 ----------------
template <typename Tin>
__global__ void transpose_cast_k(const Tin* __restrict__ in, HBF* __restrict__ out, int R, int C) {
  __shared__ float tile[32][33];
  size_t base = (size_t)blockIdx.z * R * C;
  int r0 = blockIdx.y * 32, c0 = blockIdx.x * 32;
  int tx = threadIdx.x, ty = threadIdx.y;
#pragma unroll
  for (int i = ty; i < 32; i += 8)
    tile[i][tx] = toF(in[base + (size_t)(r0 + i) * C + c0 + tx]);
  __syncthreads();
#pragma unroll
  for (int i = ty; i < 32; i += 8)
    out[base + (size_t)(c0 + i) * R + r0 + tx] = __float2bfloat16(tile[tx][i]);
}

// ---------------- GEMM: C[M,N] = A[M,K] * Bt[N,K]^T, m97-style 128x128x64 ----------------
// EPI==0: epilogue scatters to K/Q/V bf16 tensors (b,h,n,dh) with bias b_qkv (split order k,q,v)
// EPI==1: epilogue writes fp32 Cout + bias
template <int EPI>
__launch_bounds__(256)
__global__ void gemm_bt_k(const HBF* __restrict__ A, const HBF* __restrict__ Bt,
                          int M, int N, int K,
                          const float* __restrict__ bias,
                          HBF* __restrict__ Kout, HBF* __restrict__ Qout, HBF* __restrict__ Vout,
                          float* __restrict__ Cout) {
  __shared__ __align__(16) HBF As[128 * 64];
  __shared__ __align__(16) HBF Bs[128 * 64];
  const int tid = threadIdx.x;
  const int lane = tid & 63;
  const int w = tid >> 6;
  const int lo = lane & 15, g4 = lane >> 4;
  const int m0 = blockIdx.y * 128, n0 = blockIdx.x * 128;
  const int wr = w >> 1, wc = w & 1;

  const f32x4 zero = {0.f, 0.f, 0.f, 0.f};
  f32x4 acc[4][4];
#pragma unroll
  for (int i = 0; i < 4; i++)
#pragma unroll
    for (int j = 0; j < 4; j++) acc[i][j] = zero;

  for (int k0 = 0; k0 < K; k0 += 64) {
    // stage A(128x64) and Bt-rows(128x64) tiles: 16 wave-calls of 1KB each per tile
#pragma unroll
    for (int c = 0; c < 4; ++c) {
      int chunk = c * 256 + tid;           // 16B chunk id, 8 chunks per 64-elem row
      int row = chunk >> 3, kc = (chunk & 7) * 8;
      HBF* ldsA = As + (size_t)(c * 256 + w * 64) * 8;  // wave-uniform base
      HBF* ldsB = Bs + (size_t)(c * 256 + w * 64) * 8;
      gload_lds16(A + (size_t)(m0 + row) * K + k0 + kc, ldsA);
      gload_lds16(Bt + (size_t)(n0 + row) * K + k0 + kc, ldsB);
    }
    __syncthreads();  // compiler drains vmcnt(0) before barrier
#pragma unroll
    for (int kk = 0; kk < 2; ++kk) {
      bf16x8 af[4], bfr[4];
#pragma unroll
      for (int i = 0; i < 4; i++)
        af[i] = *reinterpret_cast<const bf16x8*>(As + (size_t)(wr * 64 + i * 16 + lo) * 64 + kk * 32 + g4 * 8);
#pragma unroll
      for (int j = 0; j < 4; j++)
        bfr[j] = *reinterpret_cast<const bf16x8*>(Bs + (size_t)(wc * 64 + j * 16 + lo) * 64 + kk * 32 + g4 * 8);
#pragma unroll
      for (int i = 0; i < 4; i++)
#pragma unroll
        for (int j = 0; j < 4; j++) acc[i][j] = MFMA16(af[i], bfr[j], acc[i][j]);
    }
    __syncthreads();
  }

  // epilogue. D frag: col = lane&15, row = (lane>>4)*4 + r   [m89-verified]
  if (EPI == 0) {
#pragma unroll
    for (int i = 0; i < 4; i++) {
      int mrow = m0 + wr * 64 + i * 16 + g4 * 4;
#pragma unroll
      for (int j = 0; j < 4; j++) {
        int col = n0 + wc * 64 + j * 16 + lo;  // col = h*192 + e
        int h = col / 192, e = col % 192;
        float bv = bias[col];
#pragma unroll
        for (int r = 0; r < 4; r++) {
          int m = mrow + r;
          int b = m >> 11, n = m & 2047;  // N tokens = 2048
          float v = acc[i][j][r] + bv;
          size_t idx = ((size_t)(b * 16 + h) * 2048 + n) * 64;
          if (e < 64)        Kout[idx + e]       = __float2bfloat16(v);
          else if (e < 128)  Qout[idx + e - 64]  = __float2bfloat16(v);
          else               Vout[idx + e - 128] = __float2bfloat16(v);
        }
      }
    }
  } else {
#pragma unroll
    for (int i = 0; i < 4; i++) {
      int mrow = m0 + wr * 64 + i * 16 + g4 * 4;
#pragma unroll
      for (int j = 0; j < 4; j++) {
        int col = n0 + wc * 64 + j * 16 + lo;
        float bv = bias[col];
#pragma unroll
        for (int r = 0; r < 4; r++)
          Cout[(size_t)(mrow + r) * N + col] = acc[i][j][r] + bv;
      }
    }
  }
}

// ---------------- causal flash attention ----------------
// grid (N/64, H, B), 256 threads = 4 waves; wave w handles 16 q-rows at qbase = qb*64 + w*16.
// S = mfma(Qfrag, Kfrag): row=q=(lane>>4)*4+r, col=key=lane&15. KV chunk = 32 keys.
// P transposed through padded per-wave LDS tile into A-frag layout for PV mfma.
__launch_bounds__(256)
__global__ void attn_fwd_k(const HBF* __restrict__ Qb, const HBF* __restrict__ Kb,
                           const HBF* __restrict__ Vt, HBF* __restrict__ Ob) {
  __shared__ __align__(16) HBF pLds[4][16][40];  // 40-elem pad -> 2-way conflict (free) on b128 reads
  const int tid = threadIdx.x;
  const int lane = tid & 63;
  const int w = tid >> 6;
  const int lo = lane & 15, g4 = lane >> 4;
  const int qb = blockIdx.x, h = blockIdx.y, b = blockIdx.z;
  const int bh = b * 16 + h;
  const int qbase = qb * 64 + w * 16;

  const HBF* Qp = Qb + ((size_t)bh * 2048 + qbase) * 64;
  const HBF* Kp = Kb + (size_t)bh * 2048 * 64;
  const HBF* Vp = Vt + (size_t)bh * 64 * 2048;

  // Q A-frags: lane holds Q[q=lane&15][d=(lane>>4)*8 + j (+32)]
  bf16x8 qf0 = *reinterpret_cast<const bf16x8*>(Qp + (size_t)lo * 64 + g4 * 8);
  bf16x8 qf1 = *reinterpret_cast<const bf16x8*>(Qp + (size_t)lo * 64 + 32 + g4 * 8);

  const f32x4 zero = {0.f, 0.f, 0.f, 0.f};
  f32x4 o[4];
  float mrun[4], lrun[4];
#pragma unroll
  for (int j = 0; j < 4; j++) o[j] = zero;
#pragma unroll
  for (int r = 0; r < 4; r++) { mrun[r] = -1e30f; lrun[r] = 0.f; }

  const int kvend = qbase + 16;
  for (int kv0 = 0; kv0 < kvend; kv0 += 32) {
    // S tile 16x32 as two 16x16 col halves
    f32x4 s[2];
#pragma unroll
    for (int t = 0; t < 2; t++) {
      const HBF* kp = Kp + (size_t)(kv0 + t * 16 + lo) * 64 + g4 * 8;
      bf16x8 kf0 = *reinterpret_cast<const bf16x8*>(kp);
      bf16x8 kf1 = *reinterpret_cast<const bf16x8*>(kp + 32);
      f32x4 z = zero;
      z = MFMA16(qf0, kf0, z);
      z = MFMA16(qf1, kf1, z);
      s[t] = z;
    }
    // mask + scale + row max
    float pm[4];
#pragma unroll
    for (int r = 0; r < 4; r++) {
      int qg = qbase + g4 * 4 + r;
      float s0 = (kv0 + lo <= qg) ? s[0][r] * 0.125f : -1e30f;
      float s1 = (kv0 + 16 + lo <= qg) ? s[1][r] * 0.125f : -1e30f;
      s[0][r] = s0; s[1][r] = s1;
      pm[r] = fmaxf(s0, s1);
    }
#pragma unroll
    for (int off = 1; off < 16; off <<= 1)
#pragma unroll
      for (int r = 0; r < 4; r++) pm[r] = fmaxf(pm[r], __shfl_xor(pm[r], off));

    float al[4], ps[4];
#pragma unroll
    for (int r = 0; r < 4; r++) {
      float mnew = fmaxf(mrun[r], pm[r]);
      al[r] = __expf(mrun[r] - mnew);
      mrun[r] = mnew;
      float p0 = __expf(s[0][r] - mnew);
      float p1 = __expf(s[1][r] - mnew);
      s[0][r] = p0; s[1][r] = p1;
      ps[r] = p0 + p1;
    }
#pragma unroll
    for (int off = 1; off < 16; off <<= 1)
#pragma unroll
      for (int r = 0; r < 4; r++) ps[r] += __shfl_xor(ps[r], off);
#pragma unroll
    for (int r = 0; r < 4; r++) lrun[r] = lrun[r] * al[r] + ps[r];
#pragma unroll
    for (int j = 0; j < 4; j++)
#pragma unroll
      for (int r = 0; r < 4; r++) o[j][r] *= al[r];

    // P -> per-wave LDS tile [q][k], then read back as A-frag (wave-local sync only)
#pragma unroll
    for (int t = 0; t < 2; t++)
#pragma unroll
      for (int r = 0; r < 4; r++)
        pLds[w][g4 * 4 + r][t * 16 + lo] = __float2bfloat16(s[t][r]);
    asm volatile("s_waitcnt lgkmcnt(0)" ::: "memory");
    __builtin_amdgcn_sched_barrier(0);
    bf16x8 pf = *reinterpret_cast<const bf16x8*>(&pLds[w][lo][g4 * 8]);

    // PV: O[q][d] += P(16x32) * V(32x16 per d-tile), V^T gives contiguous B-frags
#pragma unroll
    for (int j = 0; j < 4; j++) {
      bf16x8 vf = *reinterpret_cast<const bf16x8*>(Vp + (size_t)(j * 16 + lo) * 2048 + kv0 + g4 * 8);
      o[j] = MFMA16(pf, vf, o[j]);
    }
  }

  // normalize + write O (b, n, h*64+dh) bf16
#pragma unroll
  for (int r = 0; r < 4; r++) lrun[r] = 1.0f / lrun[r];
#pragma unroll
  for (int j = 0; j < 4; j++)
#pragma unroll
    for (int r = 0; r < 4; r++)
      Ob[(size_t)(b * 2048 + qbase + g4 * 4 + r) * 1024 + h * 64 + j * 16 + lo] =
          __float2bfloat16(o[j][r] * lrun[r]);
}

// ---------------- launch ----------------
extern "C" void kernel_launch(void* const* d_in, const int* in_sizes, int n_in,
                              void* d_out, int out_size, void* d_ws, size_t ws_size,
                              hipStream_t stream) {
  const float* x      = (const float*)d_in[0];
  const float* W_qkv  = (const float*)d_in[1];
  const float* b_qkv  = (const float*)d_in[2];
  const float* W_proj = (const float*)d_in[3];
  const float* b_proj = (const float*)d_in[4];
  float* out = (float*)d_out;

  const int B = 2, N = 2048, D = 1024, H = 16, DH = 64;
  const int M = B * N;  // 4096

  char* ws = (char*)d_ws;
  HBF* xb      = (HBF*)ws; ws += (size_t)M * D * 2;          // 8 MB
  HBF* wqkv_t  = (HBF*)ws; ws += (size_t)H * 3 * DH * D * 2; // 6 MB  (n'=h*192+e, k)
  HBF* wproj_t = (HBF*)ws; ws += (size_t)D * D * 2;          // 2 MB
  HBF* Qb      = (HBF*)ws; ws += (size_t)B * H * N * DH * 2; // 8 MB
  HBF* Kb      = (HBF*)ws; ws += (size_t)B * H * N * DH * 2;
  HBF* Vb      = (HBF*)ws; ws += (size_t)B * H * N * DH * 2;
  HBF* Vt      = (HBF*)ws; ws += (size_t)B * H * DH * N * 2;
  HBF* Ob      = (HBF*)ws; ws += (size_t)M * D * 2;

  // 1. x -> bf16
  cast_f32_bf16_k<<<(M * D / 4 + 255) / 256, 256, 0, stream>>>(x, xb, M * D / 4);
  // 2. W_qkv (H,D,192) -> (H,192,D) bf16
  transpose_cast_k<float><<<dim3(192 / 32, D / 32, H), dim3(32, 8), 0, stream>>>(W_qkv, wqkv_t, D, 192);
  // 3. W_proj (D,D) -> transposed bf16
  transpose_cast_k<float><<<dim3(D / 32, D / 32, 1), dim3(32, 8), 0, stream>>>(W_proj, wproj_t, D, D);
  // 4. QKV projection GEMM + scatter epilogue
  gemm_bt_k<0><<<dim3(3072 / 128, M / 128), 256, 0, stream>>>(xb, wqkv_t, M, 3 * DH * H, D,
                                                              b_qkv, Kb, Qb, Vb, nullptr);
  // 5. V (bh,N,DH) -> V^T (bh,DH,N)
  transpose_cast_k<HBF><<<dim3(DH / 32, N / 32, B * H), dim3(32, 8), 0, stream>>>(Vb, Vt, N, DH);
  // 6. flash attention
  attn_fwd_k<<<dim3(N / 64, H, B), 256, 0, stream>>>(Qb, Kb, Vt, Ob);
  // 7. output projection GEMM -> fp32 d_out
  gemm_bt_k<1><<<dim3(D / 128, M / 128), 256, 0, stream>>>(Ob, wproj_t, M, D, D,
                                                           b_proj, nullptr, nullptr, nullptr, out);
}

// Round 3
// 182.292 us; speedup vs baseline: 1.8316x; 1.8316x over previous
//
#include <hip/hip_runtime.h>
#include <hip/hip_bf16.h>

typedef __hip_bfloat16 HBF;
typedef __bf16 bf16x8 __attribute__((ext_vector_type(8)));
typedef __bf16 bf16x4 __attribute__((ext_vector_type(4)));
typedef float f32x4 __attribute__((ext_vector_type(4)));
typedef float float4v __attribute__((ext_vector_type(4)));

__device__ __forceinline__ float toF(float x) { return x; }
__device__ __forceinline__ float toF(HBF x) { return __bfloat162float(x); }

#define MFMA16(a, b, c) __builtin_amdgcn_mfma_f32_16x16x32_bf16((a), (b), (c), 0, 0, 0)

// async global->LDS, 16B per lane. LDS dest must be wave-uniform base; HW adds lane*16.
__device__ __forceinline__ void gload_lds16(const HBF* g, HBF* l) {
  __builtin_amdgcn_global_load_lds((const __attribute__((address_space(1))) void*)g,
                                   (__attribute__((address_space(3))) void*)l, 16, 0, 0);
}

// ---------------- elementwise cast f32 -> bf16 (vectorized) ----------------
struct bf4 { HBF v[4]; };
__global__ void cast_f32_bf16_k(const float* __restrict__ in, HBF* __restrict__ out, int n4) {
  int i = blockIdx.x * 256 + threadIdx.x;
  if (i >= n4) return;
  float4v a = reinterpret_cast<const float4v*>(in)[i];
  bf4 o;
  o.v[0] = __float2bfloat16(a.x); o.v[1] = __float2bfloat16(a.y);
  o.v[2] = __float2bfloat16(a.z); o.v[3] = __float2bfloat16(a.w);
  reinterpret_cast<bf4*>(out)[i] = o;
}

// ---------------- batched tiled transpose-cast: (bt,R,C) Tin -> (bt,C,R) bf16 ----------------
template <typename Tin>
__global__ void transpose_cast_k(const Tin* __restrict__ in, HBF* __restrict__ out, int R, int C) {
  __shared__ float tile[32][33];
  size_t base = (size_t)blockIdx.z * R * C;
  int r0 = blockIdx.y * 32, c0 = blockIdx.x * 32;
  int tx = threadIdx.x, ty = threadIdx.y;
#pragma unroll
  for (int i = ty; i < 32; i += 8)
    tile[i][tx] = toF(in[base + (size_t)(r0 + i) * C + c0 + tx]);
  __syncthreads();
#pragma unroll
  for (int i = ty; i < 32; i += 8)
    out[base + (size_t)(c0 + i) * R + r0 + tx] = __float2bfloat16(tile[tx][i]);
}

// ---------------- GEMM: C[M,N] = A[M,K] * Bt[N,K]^T, m97-style 128x128x64 ----------------
template <int EPI>
__launch_bounds__(256)
__global__ void gemm_bt_k(const HBF* __restrict__ A, const HBF* __restrict__ Bt,
                          int M, int N, int K,
                          const float* __restrict__ bias,
                          HBF* __restrict__ Kout, HBF* __restrict__ Qout, HBF* __restrict__ Vout,
                          float* __restrict__ Cout) {
  __shared__ __align__(16) HBF As[128 * 64];
  __shared__ __align__(16) HBF Bs[128 * 64];
  const int tid = threadIdx.x;
  const int lane = tid & 63;
  const int w = tid >> 6;
  const int lo = lane & 15, g4 = lane >> 4;
  const int m0 = blockIdx.y * 128, n0 = blockIdx.x * 128;
  const int wr = w >> 1, wc = w & 1;

  const f32x4 zero = {0.f, 0.f, 0.f, 0.f};
  f32x4 acc[4][4];
#pragma unroll
  for (int i = 0; i < 4; i++)
#pragma unroll
    for (int j = 0; j < 4; j++) acc[i][j] = zero;

  for (int k0 = 0; k0 < K; k0 += 64) {
#pragma unroll
    for (int c = 0; c < 4; ++c) {
      int chunk = c * 256 + tid;
      int row = chunk >> 3, kc = (chunk & 7) * 8;
      HBF* ldsA = As + (size_t)(c * 256 + w * 64) * 8;
      HBF* ldsB = Bs + (size_t)(c * 256 + w * 64) * 8;
      gload_lds16(A + (size_t)(m0 + row) * K + k0 + kc, ldsA);
      gload_lds16(Bt + (size_t)(n0 + row) * K + k0 + kc, ldsB);
    }
    __syncthreads();
#pragma unroll
    for (int kk = 0; kk < 2; ++kk) {
      bf16x8 af[4], bfr[4];
#pragma unroll
      for (int i = 0; i < 4; i++)
        af[i] = *reinterpret_cast<const bf16x8*>(As + (size_t)(wr * 64 + i * 16 + lo) * 64 + kk * 32 + g4 * 8);
#pragma unroll
      for (int j = 0; j < 4; j++)
        bfr[j] = *reinterpret_cast<const bf16x8*>(Bs + (size_t)(wc * 64 + j * 16 + lo) * 64 + kk * 32 + g4 * 8);
#pragma unroll
      for (int i = 0; i < 4; i++)
#pragma unroll
        for (int j = 0; j < 4; j++) acc[i][j] = MFMA16(af[i], bfr[j], acc[i][j]);
    }
    __syncthreads();
  }

  if (EPI == 0) {
#pragma unroll
    for (int i = 0; i < 4; i++) {
      int mrow = m0 + wr * 64 + i * 16 + g4 * 4;
#pragma unroll
      for (int j = 0; j < 4; j++) {
        int col = n0 + wc * 64 + j * 16 + lo;  // col = h*192 + e
        int h = col / 192, e = col % 192;
        float bv = bias[col];
#pragma unroll
        for (int r = 0; r < 4; r++) {
          int m = mrow + r;
          int b = m >> 11, n = m & 2047;
          float v = acc[i][j][r] + bv;
          size_t idx = ((size_t)(b * 16 + h) * 2048 + n) * 64;
          if (e < 64)        Kout[idx + e]       = __float2bfloat16(v);
          else if (e < 128)  Qout[idx + e - 64]  = __float2bfloat16(v);
          else               Vout[idx + e - 128] = __float2bfloat16(v);
        }
      }
    }
  } else {
#pragma unroll
    for (int i = 0; i < 4; i++) {
      int mrow = m0 + wr * 64 + i * 16 + g4 * 4;
#pragma unroll
      for (int j = 0; j < 4; j++) {
        int col = n0 + wc * 64 + j * 16 + lo;
        float bv = bias[col];
#pragma unroll
        for (int r = 0; r < 4; r++)
          Cout[(size_t)(mrow + r) * N + col] = acc[i][j][r] + bv;
      }
    }
  }
}

// ---------------- causal flash attention v2 ----------------
// grid (N/128, H, B), 256 thr = 4 waves; wave w owns 32 q-rows (2 x 16-tiles) at qw = qb*128 + w*32.
// KVBLK=64. K tile (64 key x 64 d) and V^T tile (64 d x 64 key) cooperatively staged to LDS via
// global_load_lds with PRE-SWIZZLED source (chunk ^= row&7) so swizzled ds_read_b128 is conflict-floor.
// Swapped QK^T: S^T = mfma(Kfrag, Qfrag): D col = q = lane&15, row = key = (lane>>4)*4+r.
// Softmax per lane is 15 in-reg max + shfl_xor(16,32). Defer-max THR=8 skips O-rescale.
// P -> per-wave padded LDS [32 q][72], read back as PV A-frag.
__launch_bounds__(256)
__global__ void attn_fwd_k(const HBF* __restrict__ Qb, const HBF* __restrict__ Kb,
                           const HBF* __restrict__ Vt, HBF* __restrict__ Ob) {
  __shared__ __align__(16) HBF Ks[64 * 64];
  __shared__ __align__(16) HBF Vs[64 * 64];
  __shared__ __align__(16) HBF pLds[4][32][72];  // stride 144B: 16B-aligned b128 reads, uniform-floor banks
  const int tid = threadIdx.x;
  const int lane = tid & 63;
  const int w = tid >> 6;
  const int lo = lane & 15, g4 = lane >> 4;
  const int qb = blockIdx.x, h = blockIdx.y, b = blockIdx.z;
  const int bh = b * 16 + h;
  const int bq0 = qb * 128;
  const int qw = bq0 + w * 32;

  const HBF* Qp = Qb + (size_t)bh * 2048 * 64;
  const HBF* Kp = Kb + (size_t)bh * 2048 * 64;
  const HBF* Vp = Vt + (size_t)bh * 64 * 2048;

  // Q B-frags: lane holds Q[q=lane&15][d = ds*32 + g4*8 + j]
  bf16x8 qf[2][2];
#pragma unroll
  for (int qt = 0; qt < 2; qt++)
#pragma unroll
    for (int ds = 0; ds < 2; ds++)
      qf[qt][ds] = *reinterpret_cast<const bf16x8*>(Qp + (size_t)(qw + qt * 16 + lo) * 64 + ds * 32 + g4 * 8);

  const f32x4 zero = {0.f, 0.f, 0.f, 0.f};
  f32x4 o[2][4];
  float m[2], l[2];
#pragma unroll
  for (int qt = 0; qt < 2; qt++) {
    m[qt] = -1e30f; l[qt] = 0.f;
#pragma unroll
    for (int j = 0; j < 4; j++) o[qt][j] = zero;
  }

  const int srow = (lane >> 3) & 7;  // row within 8-row staging segment
  const int sch = lane & 7;          // 16B chunk within row

  const int kvmax = bq0 + 128;
  for (int kv0 = 0; kv0 < kvmax; kv0 += 64) {
    // ---- stage K (64x64) and V^T (64x64), pre-swizzled source ----
#pragma unroll
    for (int c = 0; c < 2; c++) {
      int seg = w * 2 + c;           // 8 segments of 8 rows
      int row = seg * 8 + srow;
      gload_lds16(Kp + (size_t)(kv0 + row) * 64 + ((sch ^ (row & 7)) * 8), Ks + seg * 512);
      gload_lds16(Vp + (size_t)row * 2048 + kv0 + ((sch ^ (row & 7)) * 8), Vs + seg * 512);
    }
    __syncthreads();  // drains vmcnt before barrier -> tiles ready

    // ---- S^T = K · Q^T per 16-key tile ----
    f32x4 st[2][4];
#pragma unroll
    for (int kt = 0; kt < 4; kt++) {
      int krow = kt * 16 + lo;
      bf16x8 kf0 = *reinterpret_cast<const bf16x8*>(Ks + (size_t)krow * 64 + ((g4 ^ (krow & 7)) * 8));
      bf16x8 kf1 = *reinterpret_cast<const bf16x8*>(Ks + (size_t)krow * 64 + (((4 + g4) ^ (krow & 7)) * 8));
#pragma unroll
      for (int qt = 0; qt < 2; qt++) {
        f32x4 z = zero;
        z = MFMA16(kf0, qf[qt][0], z);
        z = MFMA16(kf1, qf[qt][1], z);
        st[qt][kt] = z;
      }
    }

    // ---- online softmax (lane-local: lane owns q = qw + qt*16 + lo) ----
#pragma unroll
    for (int qt = 0; qt < 2; qt++) {
      int q = qw + qt * 16 + lo;
      float pmax = -1e30f;
#pragma unroll
      for (int kt = 0; kt < 4; kt++)
#pragma unroll
        for (int r = 0; r < 4; r++) {
          int key = kv0 + kt * 16 + g4 * 4 + r;
          float v = (key <= q) ? st[qt][kt][r] * 0.125f : -1e30f;
          st[qt][kt][r] = v;
          pmax = fmaxf(pmax, v);
        }
      pmax = fmaxf(pmax, __shfl_xor(pmax, 16));
      pmax = fmaxf(pmax, __shfl_xor(pmax, 32));
      // defer-max: only rescale when max grew by > 8 (handles all-masked chunks for free)
      if (__any(pmax > m[qt] + 8.f)) {
        float mnew = fmaxf(m[qt], pmax);
        float al = __expf(m[qt] - mnew);
        m[qt] = mnew;
        l[qt] *= al;
        float alr[4];
#pragma unroll
        for (int r = 0; r < 4; r++) alr[r] = __shfl(al, g4 * 4 + r);  // col->row layout bcast
#pragma unroll
        for (int j = 0; j < 4; j++)
#pragma unroll
          for (int r = 0; r < 4; r++) o[qt][j][r] *= alr[r];
      }
      float ps = 0.f;
#pragma unroll
      for (int kt = 0; kt < 4; kt++)
#pragma unroll
        for (int r = 0; r < 4; r++) {
          float p = __expf(st[qt][kt][r] - m[qt]);
          st[qt][kt][r] = p;
          ps += p;
        }
      ps += __shfl_xor(ps, 16);
      ps += __shfl_xor(ps, 32);
      l[qt] += ps;
      // pack P row (q = lo) keys kt*16 + g4*4 + 0..3 -> b64 writes
#pragma unroll
      for (int kt = 0; kt < 4; kt++) {
        bf16x4 pk;
#pragma unroll
        for (int r = 0; r < 4; r++) pk[r] = (__bf16)st[qt][kt][r];
        *reinterpret_cast<bf16x4*>(&pLds[w][qt * 16 + lo][kt * 16 + g4 * 4]) = pk;
      }
    }

    // ---- PV: O[q][d] += P(32q x 64k) · V(64k x 64d); compiler orders pLds RAW ----
    bf16x8 pa[2][2];
#pragma unroll
    for (int qt = 0; qt < 2; qt++)
#pragma unroll
      for (int ks = 0; ks < 2; ks++)
        pa[qt][ks] = *reinterpret_cast<const bf16x8*>(&pLds[w][qt * 16 + lo][ks * 32 + g4 * 8]);
#pragma unroll
    for (int j = 0; j < 4; j++) {
      int vrow = j * 16 + lo;
#pragma unroll
      for (int ks = 0; ks < 2; ks++) {
        bf16x8 vb = *reinterpret_cast<const bf16x8*>(Vs + (size_t)vrow * 64 + (((ks * 4 + g4) ^ (vrow & 7)) * 8));
#pragma unroll
        for (int qt = 0; qt < 2; qt++) o[qt][j] = MFMA16(pa[qt][ks], vb, o[qt][j]);
      }
    }
    __syncthreads();  // protect LDS tiles before next stage overwrites
  }

  // ---- epilogue: rows q = qw + qt*16 + g4*4 + r, cols d = h*64 + j*16 + lo ----
#pragma unroll
  for (int qt = 0; qt < 2; qt++) {
    float linv = 1.f / l[qt];
    float lr[4];
#pragma unroll
    for (int r = 0; r < 4; r++) lr[r] = __shfl(linv, g4 * 4 + r);
#pragma unroll
    for (int j = 0; j < 4; j++)
#pragma unroll
      for (int r = 0; r < 4; r++) {
        int q = qw + qt * 16 + g4 * 4 + r;
        Ob[(size_t)(b * 2048 + q) * 1024 + h * 64 + j * 16 + lo] =
            __float2bfloat16(o[qt][j][r] * lr[r]);
      }
  }
}

// ---------------- launch ----------------
extern "C" void kernel_launch(void* const* d_in, const int* in_sizes, int n_in,
                              void* d_out, int out_size, void* d_ws, size_t ws_size,
                              hipStream_t stream) {
  const float* x      = (const float*)d_in[0];
  const float* W_qkv  = (const float*)d_in[1];
  const float* b_qkv  = (const float*)d_in[2];
  const float* W_proj = (const float*)d_in[3];
  const float* b_proj = (const float*)d_in[4];
  float* out = (float*)d_out;

  const int B = 2, N = 2048, D = 1024, H = 16, DH = 64;
  const int M = B * N;  // 4096

  char* ws = (char*)d_ws;
  HBF* xb      = (HBF*)ws; ws += (size_t)M * D * 2;
  HBF* wqkv_t  = (HBF*)ws; ws += (size_t)H * 3 * DH * D * 2;
  HBF* wproj_t = (HBF*)ws; ws += (size_t)D * D * 2;
  HBF* Qb      = (HBF*)ws; ws += (size_t)B * H * N * DH * 2;
  HBF* Kb      = (HBF*)ws; ws += (size_t)B * H * N * DH * 2;
  HBF* Vb      = (HBF*)ws; ws += (size_t)B * H * N * DH * 2;
  HBF* Vt      = (HBF*)ws; ws += (size_t)B * H * DH * N * 2;
  HBF* Ob      = (HBF*)ws; ws += (size_t)M * D * 2;

  cast_f32_bf16_k<<<(M * D / 4 + 255) / 256, 256, 0, stream>>>(x, xb, M * D / 4);
  transpose_cast_k<float><<<dim3(192 / 32, D / 32, H), dim3(32, 8), 0, stream>>>(W_qkv, wqkv_t, D, 192);
  transpose_cast_k<float><<<dim3(D / 32, D / 32, 1), dim3(32, 8), 0, stream>>>(W_proj, wproj_t, D, D);
  gemm_bt_k<0><<<dim3(3072 / 128, M / 128), 256, 0, stream>>>(xb, wqkv_t, M, 3 * DH * H, D,
                                                              b_qkv, Kb, Qb, Vb, nullptr);
  transpose_cast_k<HBF><<<dim3(DH / 32, N / 32, B * H), dim3(32, 8), 0, stream>>>(Vb, Vt, N, DH);
  attn_fwd_k<<<dim3(N / 128, H, B), 256, 0, stream>>>(Qb, Kb, Vt, Ob);
  gemm_bt_k<1><<<dim3(D / 128, M / 128), 256, 0, stream>>>(Ob, wproj_t, M, D, D,
                                                           b_proj, nullptr, nullptr, nullptr, out);
}

// Round 5
// 160.856 us; speedup vs baseline: 2.0757x; 1.1333x over previous
//
#include <hip/hip_runtime.h>
#include <hip/hip_bf16.h>

typedef __hip_bfloat16 HBF;
typedef __bf16 bf16x8 __attribute__((ext_vector_type(8)));
typedef __bf16 bf16x4 __attribute__((ext_vector_type(4)));
typedef float f32x4 __attribute__((ext_vector_type(4)));
typedef float float4v __attribute__((ext_vector_type(4)));

__device__ __forceinline__ float toF(float x) { return x; }
__device__ __forceinline__ float toF(HBF x) { return __bfloat162float(x); }

#define MFMA16(a, b, c) __builtin_amdgcn_mfma_f32_16x16x32_bf16((a), (b), (c), 0, 0, 0)

// hardware exp2: v_exp_f32 computes 2^x directly
#define EXP2F(x) __builtin_amdgcn_exp2f(x)

// Q pre-scale: 1/sqrt(64) * log2(e) -> scores land in exp2 domain
#define QSCALE 0.18033688011112042f

// async global->LDS, 16B per lane. LDS dest must be wave-uniform base; HW adds lane*16.
__device__ __forceinline__ void gload_lds16(const HBF* g, HBF* l) {
  __builtin_amdgcn_global_load_lds((const __attribute__((address_space(1))) void*)g,
                                   (__attribute__((address_space(3))) void*)l, 16, 0, 0);
}

// ---------------- elementwise cast f32 -> bf16 (vectorized) ----------------
struct bf4 { HBF v[4]; };
__global__ void cast_f32_bf16_k(const float* __restrict__ in, HBF* __restrict__ out, int n4) {
  int i = blockIdx.x * 256 + threadIdx.x;
  if (i >= n4) return;
  float4v a = reinterpret_cast<const float4v*>(in)[i];
  bf4 o;
  o.v[0] = __float2bfloat16(a.x); o.v[1] = __float2bfloat16(a.y);
  o.v[2] = __float2bfloat16(a.z); o.v[3] = __float2bfloat16(a.w);
  reinterpret_cast<bf4*>(out)[i] = o;
}

// ---------------- batched tiled transpose-cast: (bt,R,C) f32 -> (bt,C,R) bf16 ----------------
template <typename Tin>
__global__ void transpose_cast_k(const Tin* __restrict__ in, HBF* __restrict__ out, int R, int C) {
  __shared__ float tile[32][33];
  size_t base = (size_t)blockIdx.z * R * C;
  int r0 = blockIdx.y * 32, c0 = blockIdx.x * 32;
  int tx = threadIdx.x, ty = threadIdx.y;
#pragma unroll
  for (int i = ty; i < 32; i += 8)
    tile[i][tx] = toF(in[base + (size_t)(r0 + i) * C + c0 + tx]);
  __syncthreads();
#pragma unroll
  for (int i = ty; i < 32; i += 8)
    out[base + (size_t)(c0 + i) * R + r0 + tx] = __float2bfloat16(tile[tx][i]);
}

// ---------------- GEMM: C[M,N] = A[M,K] * Bt[N,K]^T, m97-style 128x128x64 ----------------
// EPI==0: scatter epilogue -> K (b,h,n,dh), Q scaled by QSCALE, V written TRANSPOSED (b,h,dh,n)
// EPI==1: fp32 Cout + bias
template <int EPI>
__launch_bounds__(256)
__global__ void gemm_bt_k(const HBF* __restrict__ A, const HBF* __restrict__ Bt,
                          int M, int N, int K,
                          const float* __restrict__ bias,
                          HBF* __restrict__ Kout, HBF* __restrict__ Qout, HBF* __restrict__ Vtout,
                          float* __restrict__ Cout) {
  __shared__ __align__(16) HBF As[128 * 64];
  __shared__ __align__(16) HBF Bs[128 * 64];
  const int tid = threadIdx.x;
  const int lane = tid & 63;
  const int w = tid >> 6;
  const int lo = lane & 15, g4 = lane >> 4;
  const int m0 = blockIdx.y * 128, n0 = blockIdx.x * 128;
  const int wr = w >> 1, wc = w & 1;

  const f32x4 zero = {0.f, 0.f, 0.f, 0.f};
  f32x4 acc[4][4];
#pragma unroll
  for (int i = 0; i < 4; i++)
#pragma unroll
    for (int j = 0; j < 4; j++) acc[i][j] = zero;

  for (int k0 = 0; k0 < K; k0 += 64) {
#pragma unroll
    for (int c = 0; c < 4; ++c) {
      int chunk = c * 256 + tid;
      int row = chunk >> 3, kc = (chunk & 7) * 8;
      HBF* ldsA = As + (size_t)(c * 256 + w * 64) * 8;
      HBF* ldsB = Bs + (size_t)(c * 256 + w * 64) * 8;
      gload_lds16(A + (size_t)(m0 + row) * K + k0 + kc, ldsA);
      gload_lds16(Bt + (size_t)(n0 + row) * K + k0 + kc, ldsB);
    }
    __syncthreads();
#pragma unroll
    for (int kk = 0; kk < 2; ++kk) {
      bf16x8 af[4], bfr[4];
#pragma unroll
      for (int i = 0; i < 4; i++)
        af[i] = *reinterpret_cast<const bf16x8*>(As + (size_t)(wr * 64 + i * 16 + lo) * 64 + kk * 32 + g4 * 8);
#pragma unroll
      for (int j = 0; j < 4; j++)
        bfr[j] = *reinterpret_cast<const bf16x8*>(Bs + (size_t)(wc * 64 + j * 16 + lo) * 64 + kk * 32 + g4 * 8);
#pragma unroll
      for (int i = 0; i < 4; i++)
#pragma unroll
        for (int j = 0; j < 4; j++) acc[i][j] = MFMA16(af[i], bfr[j], acc[i][j]);
    }
    __syncthreads();
  }

  if (EPI == 0) {
#pragma unroll
    for (int i = 0; i < 4; i++) {
      int mrow = m0 + wr * 64 + i * 16 + g4 * 4;
#pragma unroll
      for (int j = 0; j < 4; j++) {
        int col = n0 + wc * 64 + j * 16 + lo;  // col = h*192 + e
        int h = col / 192, e = col % 192;
        float bv = bias[col];
#pragma unroll
        for (int r = 0; r < 4; r++) {
          int m = mrow + r;
          int b = m >> 11, n = m & 2047;
          float v = acc[i][j][r] + bv;
          size_t bh64 = (size_t)(b * 16 + h);
          if (e < 64)        Kout[(bh64 * 2048 + n) * 64 + e] = __float2bfloat16(v);
          else if (e < 128)  Qout[(bh64 * 2048 + n) * 64 + e - 64] = __float2bfloat16(v * QSCALE);
          else               Vtout[(bh64 * 64 + (e - 128)) * 2048 + n] = __float2bfloat16(v);
        }
      }
    }
  } else {
#pragma unroll
    for (int i = 0; i < 4; i++) {
      int mrow = m0 + wr * 64 + i * 16 + g4 * 4;
#pragma unroll
      for (int j = 0; j < 4; j++) {
        int col = n0 + wc * 64 + j * 16 + lo;
        float bv = bias[col];
#pragma unroll
        for (int r = 0; r < 4; r++)
          Cout[(size_t)(mrow + r) * N + col] = acc[i][j][r] + bv;
      }
    }
  }
}

// ---------------- causal flash attention v3: diagonal-paired, double-buffered ----------------
// grid (16, H, B), 256 thr = 4 waves. Block i owns q-tiles tA=i and tB=31-i (64 rows each);
// wave w owns rows base + w*16 of each -> work per block is uniform (33 kv-units).
// KVBLK=64, K/V^T staged to LDS double-buffered (issue at iter top, drain at iter-end barrier).
// Swapped QK^T (S^T via mfma(K,Q)), lane-local online softmax in exp2 domain (Q pre-scaled),
// diagonal-only masking, defer-max THR=11.5 (=8 ln-units).
__launch_bounds__(256)
__global__ void attn_fwd_k(const HBF* __restrict__ Qb, const HBF* __restrict__ Kb,
                           const HBF* __restrict__ Vt, HBF* __restrict__ Ob) {
  __shared__ __align__(16) HBF Ks[2][64 * 64];
  __shared__ __align__(16) HBF Vs[2][64 * 64];
  __shared__ __align__(16) HBF pLds[4][2][16][72];
  const int tid = threadIdx.x;
  const int lane = tid & 63;
  const int w = tid >> 6;
  const int lo = lane & 15, g4 = lane >> 4;
  const int i = blockIdx.x, h = blockIdx.y, b = blockIdx.z;
  const int bh = b * 16 + h;
  const int baseT[2] = { i * 64 + w * 16, (31 - i) * 64 + w * 16 };
  const int nkv = 32 - i;

  const HBF* Qp = Qb + (size_t)bh * 2048 * 64;
  const HBF* Kp = Kb + (size_t)bh * 2048 * 64;
  const HBF* Vp = Vt + (size_t)bh * 64 * 2048;

  // Q B-frags (pre-scaled by QSCALE in GEMM epilogue)
  bf16x8 qf[2][2];
#pragma unroll
  for (int qt = 0; qt < 2; qt++)
#pragma unroll
    for (int ds = 0; ds < 2; ds++)
      qf[qt][ds] = *reinterpret_cast<const bf16x8*>(Qp + (size_t)(baseT[qt] + lo) * 64 + ds * 32 + g4 * 8);

  const f32x4 zero = {0.f, 0.f, 0.f, 0.f};
  f32x4 o[2][4];
  float m[2], l[2];
#pragma unroll
  for (int qt = 0; qt < 2; qt++) {
    m[qt] = -1e30f; l[qt] = 0.f;
#pragma unroll
    for (int j = 0; j < 4; j++) o[qt][j] = zero;
  }

  const int srow = (lane >> 3) & 7;  // row within 8-row staging segment
  const int sch = lane & 7;          // 16B chunk within row

  auto stage = [&](int kv0, int sb) {
#pragma unroll
    for (int c = 0; c < 2; c++) {
      int seg = w * 2 + c;
      int row = seg * 8 + srow;
      gload_lds16(Kp + (size_t)(kv0 + row) * 64 + ((sch ^ (row & 7)) * 8), &Ks[sb][seg * 512]);
      gload_lds16(Vp + (size_t)row * 2048 + kv0 + ((sch ^ (row & 7)) * 8), &Vs[sb][seg * 512]);
    }
  };

  stage(0, 0);
  __syncthreads();

  for (int t = 0; t < nkv; ++t) {
    const int kv0 = t * 64;
    const int sb = t & 1;
    if (t + 1 < nkv) stage(kv0 + 64, sb ^ 1);  // prefetch under compute
    const bool doA = (t <= i);
    const bool diagT[2] = { t == i, t == nkv - 1 };

    // ---- S^T = K · Q^T, shared K-frags across both q-tiles ----
    f32x4 st[2][4];
#pragma unroll
    for (int kt = 0; kt < 4; kt++) {
      int krow = kt * 16 + lo;
      bf16x8 kf0 = *reinterpret_cast<const bf16x8*>(&Ks[sb][krow * 64 + ((g4 ^ (krow & 7)) * 8)]);
      bf16x8 kf1 = *reinterpret_cast<const bf16x8*>(&Ks[sb][krow * 64 + (((4 + g4) ^ (krow & 7)) * 8)]);
      f32x4 z = zero;
      z = MFMA16(kf0, qf[1][0], z);
      z = MFMA16(kf1, qf[1][1], z);
      st[1][kt] = z;
      if (doA) {
        f32x4 y = zero;
        y = MFMA16(kf0, qf[0][0], y);
        y = MFMA16(kf1, qf[0][1], y);
        st[0][kt] = y;
      }
    }

    // ---- per-tile online softmax (lane owns q-col = baseT+lo) + pack P ----
#pragma unroll
    for (int qt = 0; qt < 2; qt++) {
      if (qt == 0 && !doA) continue;
      const int q = baseT[qt] + lo;
      float pmax = -1e30f;
      if (diagT[qt]) {
#pragma unroll
        for (int kt = 0; kt < 4; kt++)
#pragma unroll
          for (int r = 0; r < 4; r++) {
            int key = kv0 + kt * 16 + g4 * 4 + r;
            float v = (key <= q) ? st[qt][kt][r] : -1e30f;
            st[qt][kt][r] = v;
            pmax = fmaxf(pmax, v);
          }
      } else {
#pragma unroll
        for (int kt = 0; kt < 4; kt++)
#pragma unroll
          for (int r = 0; r < 4; r++) pmax = fmaxf(pmax, st[qt][kt][r]);
      }
      pmax = fmaxf(pmax, __shfl_xor(pmax, 16));
      pmax = fmaxf(pmax, __shfl_xor(pmax, 32));
      if (__any(pmax > m[qt] + 11.5f)) {  // defer-max (8 ln-units in log2 domain)
        float mn = fmaxf(m[qt], pmax);
        float al = EXP2F(m[qt] - mn);
        m[qt] = mn;
        l[qt] *= al;
        float alr[4];
#pragma unroll
        for (int r = 0; r < 4; r++) alr[r] = __shfl(al, g4 * 4 + r);
#pragma unroll
        for (int j = 0; j < 4; j++)
#pragma unroll
          for (int r = 0; r < 4; r++) o[qt][j][r] *= alr[r];
      }
      float ps = 0.f;
#pragma unroll
      for (int kt = 0; kt < 4; kt++)
#pragma unroll
        for (int r = 0; r < 4; r++) {
          float p = EXP2F(st[qt][kt][r] - m[qt]);
          st[qt][kt][r] = p;
          ps += p;
        }
      ps += __shfl_xor(ps, 16);
      ps += __shfl_xor(ps, 32);
      l[qt] += ps;
#pragma unroll
      for (int kt = 0; kt < 4; kt++) {
        bf16x4 pk;
#pragma unroll
        for (int r = 0; r < 4; r++) pk[r] = (__bf16)st[qt][kt][r];
        *reinterpret_cast<bf16x4*>(&pLds[w][qt][lo][kt * 16 + g4 * 4]) = pk;
      }
    }

    // ---- PV, shared V-frags across both q-tiles ----
    bf16x8 paA[2], paB[2];
#pragma unroll
    for (int ks = 0; ks < 2; ks++) {
      paB[ks] = *reinterpret_cast<const bf16x8*>(&pLds[w][1][lo][ks * 32 + g4 * 8]);
      if (doA) paA[ks] = *reinterpret_cast<const bf16x8*>(&pLds[w][0][lo][ks * 32 + g4 * 8]);
    }
#pragma unroll
    for (int j = 0; j < 4; j++) {
      int vrow = j * 16 + lo;
#pragma unroll
      for (int ks = 0; ks < 2; ks++) {
        bf16x8 vb = *reinterpret_cast<const bf16x8*>(&Vs[sb][vrow * 64 + (((ks * 4 + g4) ^ (vrow & 7)) * 8)]);
        o[1][j] = MFMA16(paB[ks], vb, o[1][j]);
        if (doA) o[0][j] = MFMA16(paA[ks], vb, o[0][j]);
      }
    }
    __syncthreads();  // drains this iter's prefetch (had full compute phase) + protects LDS reuse
  }

  // ---- epilogue ----
#pragma unroll
  for (int qt = 0; qt < 2; qt++) {
    float linv = 1.f / l[qt];
    float lr[4];
#pragma unroll
    for (int r = 0; r < 4; r++) lr[r] = __shfl(linv, g4 * 4 + r);
#pragma unroll
    for (int j = 0; j < 4; j++)
#pragma unroll
      for (int r = 0; r < 4; r++) {
        int q = baseT[qt] + g4 * 4 + r;
        Ob[(size_t)(b * 2048 + q) * 1024 + h * 64 + j * 16 + lo] =
            __float2bfloat16(o[qt][j][r] * lr[r]);
      }
  }
}

// ---------------- launch ----------------
extern "C" void kernel_launch(void* const* d_in, const int* in_sizes, int n_in,
                              void* d_out, int out_size, void* d_ws, size_t ws_size,
                              hipStream_t stream) {
  const float* x      = (const float*)d_in[0];
  const float* W_qkv  = (const float*)d_in[1];
  const float* b_qkv  = (const float*)d_in[2];
  const float* W_proj = (const float*)d_in[3];
  const float* b_proj = (const float*)d_in[4];
  float* out = (float*)d_out;

  const int B = 2, N = 2048, D = 1024, H = 16, DH = 64;
  const int M = B * N;  // 4096

  char* ws = (char*)d_ws;
  HBF* xb      = (HBF*)ws; ws += (size_t)M * D * 2;
  HBF* wqkv_t  = (HBF*)ws; ws += (size_t)H * 3 * DH * D * 2;
  HBF* wproj_t = (HBF*)ws; ws += (size_t)D * D * 2;
  HBF* Qb      = (HBF*)ws; ws += (size_t)B * H * N * DH * 2;
  HBF* Kb      = (HBF*)ws; ws += (size_t)B * H * N * DH * 2;
  HBF* Vt      = (HBF*)ws; ws += (size_t)B * H * DH * N * 2;
  HBF* Ob      = (HBF*)ws; ws += (size_t)M * D * 2;

  cast_f32_bf16_k<<<(M * D / 4 + 255) / 256, 256, 0, stream>>>(x, xb, M * D / 4);
  transpose_cast_k<float><<<dim3(192 / 32, D / 32, H), dim3(32, 8), 0, stream>>>(W_qkv, wqkv_t, D, 192);
  transpose_cast_k<float><<<dim3(D / 32, D / 32, 1), dim3(32, 8), 0, stream>>>(W_proj, wproj_t, D, D);
  // QKV GEMM: scatter K, Q (pre-scaled), V^T directly
  gemm_bt_k<0><<<dim3(3072 / 128, M / 128), 256, 0, stream>>>(xb, wqkv_t, M, 3 * DH * H, D,
                                                              b_qkv, Kb, Qb, Vt, nullptr);
  attn_fwd_k<<<dim3(16, H, B), 256, 0, stream>>>(Qb, Kb, Vt, Ob);
  gemm_bt_k<1><<<dim3(D / 128, M / 128), 256, 0, stream>>>(Ob, wproj_t, M, D, D,
                                                           b_proj, nullptr, nullptr, nullptr, out);
}

// Round 6
// 146.248 us; speedup vs baseline: 2.2830x; 1.0999x over previous
//
#include <hip/hip_runtime.h>
#include <hip/hip_bf16.h>

typedef __hip_bfloat16 HBF;
typedef __bf16 bf16x8 __attribute__((ext_vector_type(8)));
typedef __bf16 bf16x4 __attribute__((ext_vector_type(4)));
typedef float f32x4 __attribute__((ext_vector_type(4)));
typedef float float4v __attribute__((ext_vector_type(4)));

__device__ __forceinline__ float toF(float x) { return x; }
__device__ __forceinline__ float toF(HBF x) { return __bfloat162float(x); }

#define MFMA16(a, b, c) __builtin_amdgcn_mfma_f32_16x16x32_bf16((a), (b), (c), 0, 0, 0)
#define EXP2F(x) __builtin_amdgcn_exp2f(x)
#define QSCALE 0.18033688011112042f
#define MEMFENCE asm volatile("" ::: "memory")

// async global->LDS, 16B per lane. LDS dest must be wave-uniform base; HW adds lane*16.
__device__ __forceinline__ void gload_lds16(const HBF* g, HBF* l) {
  __builtin_amdgcn_global_load_lds((const __attribute__((address_space(1))) void*)g,
                                   (__attribute__((address_space(3))) void*)l, 16, 0, 0);
}

// ---------------- elementwise cast f32 -> bf16 ----------------
struct bf4 { HBF v[4]; };
__global__ void cast_f32_bf16_k(const float* __restrict__ in, HBF* __restrict__ out, int n4) {
  int i = blockIdx.x * 256 + threadIdx.x;
  if (i >= n4) return;
  float4v a = reinterpret_cast<const float4v*>(in)[i];
  bf4 o;
  o.v[0] = __float2bfloat16(a.x); o.v[1] = __float2bfloat16(a.y);
  o.v[2] = __float2bfloat16(a.z); o.v[3] = __float2bfloat16(a.w);
  reinterpret_cast<bf4*>(out)[i] = o;
}

// ---------------- batched tiled transpose-cast ----------------
template <typename Tin>
__global__ void transpose_cast_k(const Tin* __restrict__ in, HBF* __restrict__ out, int R, int C) {
  __shared__ float tile[32][33];
  size_t base = (size_t)blockIdx.z * R * C;
  int r0 = blockIdx.y * 32, c0 = blockIdx.x * 32;
  int tx = threadIdx.x, ty = threadIdx.y;
#pragma unroll
  for (int i = ty; i < 32; i += 8)
    tile[i][tx] = toF(in[base + (size_t)(r0 + i) * C + c0 + tx]);
  __syncthreads();
#pragma unroll
  for (int i = ty; i < 32; i += 8)
    out[base + (size_t)(c0 + i) * R + r0 + tx] = __float2bfloat16(tile[tx][i]);
}

// ---------------- QKV GEMM: 256x256x64, 8-phase, swizzled LDS, counted vmcnt ----------------
// C[4096,3072] = xb[4096,1024] * wqkv_t[3072,1024]^T, scatter epilogue -> K, Q*QSCALE, V^T.
// 8 waves (2M x 4N), per-wave C = 128x64. K-tiles of 64, double-buffered (128KB LDS).
// Half-tile stream (4/K-tile: A0,A1,B0,B1) issues 6 ahead; vmcnt(4) once per tile at P3.
// LDS swizzle: chunk ^= row&7 on both staging source and ds_read (involution, 2-way conflicts).
__launch_bounds__(512, 2)
__global__ void gemm_qkv_8ph(const HBF* __restrict__ A, const HBF* __restrict__ Bt,
                             const float* __restrict__ bias,
                             HBF* __restrict__ Kout, HBF* __restrict__ Qout,
                             HBF* __restrict__ Vtout) {
  __shared__ __align__(16) HBF As[2][16384];
  __shared__ __align__(16) HBF Bs[2][16384];
  const int tid = threadIdx.x, lane = tid & 63, w = tid >> 6;
  const int lo = lane & 15, g4 = lane >> 4;
  const int wr = w >> 2, wc = w & 3;
  // XCD-aware bijective swizzle: 192 = 8 * 24
  const int s = ((int)blockIdx.x & 7) * 24 + ((int)blockIdx.x >> 3);
  const int bx = s % 12, by = s / 12;
  const int m0 = by * 256, n0 = bx * 256;
  const int NT = 16;  // K=1024 / 64

  f32x4 acc[8][4];
#pragma unroll
  for (int i = 0; i < 8; i++)
#pragma unroll
    for (int j = 0; j < 4; j++) acc[i][j] = (f32x4){0.f, 0.f, 0.f, 0.f};
  bf16x8 af[8][2], bfr[4][2];

  const int rl0 = w * 8 + (lane >> 3);       // staging row for c=0
  const int rl1 = 64 + rl0;                  // c=1
  const int kc0 = (lane & 7) ^ (rl0 & 7);    // pre-swizzled chunk
  const int kc1 = (lane & 7) ^ (rl1 & 7);

  // stage half-tile j: kt=j>>2, type j&3 in {A0,A1,B0,B1}
  auto stageH = [&](int j) {
    const int kt = j >> 2, ty = j & 3, bb = kt & 1, hf = ty & 1;
    HBF* base = (ty < 2) ? &As[bb][hf * 8192] : &Bs[bb][hf * 8192];
    const HBF* g = (ty < 2) ? A : Bt;
    const int r0g = ((ty < 2) ? m0 : n0) + hf * 128;
    gload_lds16(g + (size_t)(r0g + rl0) * 1024 + kt * 64 + kc0 * 8, base + w * 512);
    gload_lds16(g + (size_t)(r0g + rl1) * 1024 + kt * 64 + kc1 * 8, base + 4096 + w * 512);
  };
  auto ldA = [&](int bb, int mt, int ks) -> bf16x8 {
    int row = wr * 128 + mt * 16 + lo;
    return *reinterpret_cast<const bf16x8*>(&As[bb][row * 64 + ((ks * 32 + g4 * 8) ^ ((row & 7) * 8))]);
  };
  auto ldB = [&](int bb, int nt, int ks) -> bf16x8 {
    int row = wc * 64 + nt * 16 + lo;
    return *reinterpret_cast<const bf16x8*>(&Bs[bb][row * 64 + ((ks * 32 + g4 * 8) ^ ((row & 7) * 8))]);
  };

  // prologue: tile0 (4 halves) + tile1 A-halves; wait tile0 (2 halves may fly)
  stageH(0); stageH(1); stageH(2); stageH(3); stageH(4); stageH(5);
  asm volatile("s_waitcnt vmcnt(4)" ::: "memory");
  __builtin_amdgcn_s_barrier();
  MEMFENCE;

  for (int t = 0; t < NT; ++t) {
    const int bb = t & 1;
    // ---- P0: read A m0-3, B n0-1; stage; MFMA m0-3 x n0-1 ----
#pragma unroll
    for (int mt = 0; mt < 4; ++mt) { af[mt][0] = ldA(bb, mt, 0); af[mt][1] = ldA(bb, mt, 1); }
#pragma unroll
    for (int nt = 0; nt < 2; ++nt) { bfr[nt][0] = ldB(bb, nt, 0); bfr[nt][1] = ldB(bb, nt, 1); }
    { int j = 4 * t + 6; if (j < 4 * NT) stageH(j); }
    MEMFENCE; __builtin_amdgcn_s_barrier(); MEMFENCE;
    __builtin_amdgcn_s_setprio(1);
#pragma unroll
    for (int mt = 0; mt < 4; ++mt)
#pragma unroll
      for (int nt = 0; nt < 2; ++nt)
#pragma unroll
        for (int ks = 0; ks < 2; ++ks) acc[mt][nt] = MFMA16(af[mt][ks], bfr[nt][ks], acc[mt][nt]);
    __builtin_amdgcn_s_setprio(0);
    MEMFENCE; __builtin_amdgcn_s_barrier(); MEMFENCE;
    // ---- P1: read A m4-7, B n2-3; stage; MFMA m4-7 x n0-1 ----
#pragma unroll
    for (int mt = 4; mt < 8; ++mt) { af[mt][0] = ldA(bb, mt, 0); af[mt][1] = ldA(bb, mt, 1); }
#pragma unroll
    for (int nt = 2; nt < 4; ++nt) { bfr[nt][0] = ldB(bb, nt, 0); bfr[nt][1] = ldB(bb, nt, 1); }
    { int j = 4 * t + 7; if (j < 4 * NT) stageH(j); }
    MEMFENCE; __builtin_amdgcn_s_barrier(); MEMFENCE;
    __builtin_amdgcn_s_setprio(1);
#pragma unroll
    for (int mt = 4; mt < 8; ++mt)
#pragma unroll
      for (int nt = 0; nt < 2; ++nt)
#pragma unroll
        for (int ks = 0; ks < 2; ++ks) acc[mt][nt] = MFMA16(af[mt][ks], bfr[nt][ks], acc[mt][nt]);
    __builtin_amdgcn_s_setprio(0);
    MEMFENCE; __builtin_amdgcn_s_barrier(); MEMFENCE;
    // ---- P2: stage; MFMA m0-3 x n2-3 (regs) ----
    { int j = 4 * t + 8; if (j < 4 * NT) stageH(j); }
    MEMFENCE; __builtin_amdgcn_s_barrier(); MEMFENCE;
    __builtin_amdgcn_s_setprio(1);
#pragma unroll
    for (int mt = 0; mt < 4; ++mt)
#pragma unroll
      for (int nt = 2; nt < 4; ++nt)
#pragma unroll
        for (int ks = 0; ks < 2; ++ks) acc[mt][nt] = MFMA16(af[mt][ks], bfr[nt][ks], acc[mt][nt]);
    __builtin_amdgcn_s_setprio(0);
    MEMFENCE; __builtin_amdgcn_s_barrier(); MEMFENCE;
    // ---- P3: stage; MFMA m4-7 x n2-3; vmcnt(4); barrier ----
    { int j = 4 * t + 9; if (j < 4 * NT) stageH(j); }
    MEMFENCE; __builtin_amdgcn_s_barrier(); MEMFENCE;
    __builtin_amdgcn_s_setprio(1);
#pragma unroll
    for (int mt = 4; mt < 8; ++mt)
#pragma unroll
      for (int nt = 2; nt < 4; ++nt)
#pragma unroll
        for (int ks = 0; ks < 2; ++ks) acc[mt][nt] = MFMA16(af[mt][ks], bfr[nt][ks], acc[mt][nt]);
    __builtin_amdgcn_s_setprio(0);
    asm volatile("s_waitcnt vmcnt(4)" ::: "memory");
    __builtin_amdgcn_s_barrier();
    MEMFENCE;
  }

  // ---- scatter epilogue: col = h*192+e -> K / Q*QSCALE / V^T ----
#pragma unroll
  for (int mt = 0; mt < 8; ++mt) {
    int mrow = m0 + wr * 128 + mt * 16 + g4 * 4;
#pragma unroll
    for (int nt = 0; nt < 4; ++nt) {
      int col = n0 + wc * 64 + nt * 16 + lo;
      int h = col / 192, e = col % 192;
      float bv = bias[col];
#pragma unroll
      for (int r = 0; r < 4; ++r) {
        int mm = mrow + r;
        int b = mm >> 11, n = mm & 2047;
        float v = acc[mt][nt][r] + bv;
        size_t bh64 = (size_t)(b * 16 + h);
        if (e < 64)       Kout[(bh64 * 2048 + n) * 64 + e] = __float2bfloat16(v);
        else if (e < 128) Qout[(bh64 * 2048 + n) * 64 + e - 64] = __float2bfloat16(v * QSCALE);
        else              Vtout[(bh64 * 64 + (e - 128)) * 2048 + n] = __float2bfloat16(v);
      }
    }
  }
}

// ---------------- proj GEMM: m97-style 128x128x64, fp32 out + bias ----------------
__launch_bounds__(256)
__global__ void gemm_proj_k(const HBF* __restrict__ A, const HBF* __restrict__ Bt,
                            int M, int N, int K, const float* __restrict__ bias,
                            float* __restrict__ Cout) {
  __shared__ __align__(16) HBF As[128 * 64];
  __shared__ __align__(16) HBF Bs[128 * 64];
  const int tid = threadIdx.x;
  const int lane = tid & 63;
  const int w = tid >> 6;
  const int lo = lane & 15, g4 = lane >> 4;
  const int m0 = blockIdx.y * 128, n0 = blockIdx.x * 128;
  const int wr = w >> 1, wc = w & 1;

  const f32x4 zero = {0.f, 0.f, 0.f, 0.f};
  f32x4 acc[4][4];
#pragma unroll
  for (int i = 0; i < 4; i++)
#pragma unroll
    for (int j = 0; j < 4; j++) acc[i][j] = zero;

  for (int k0 = 0; k0 < K; k0 += 64) {
#pragma unroll
    for (int c = 0; c < 4; ++c) {
      int chunk = c * 256 + tid;
      int row = chunk >> 3, kc = (chunk & 7) * 8;
      HBF* ldsA = As + (size_t)(c * 256 + w * 64) * 8;
      HBF* ldsB = Bs + (size_t)(c * 256 + w * 64) * 8;
      gload_lds16(A + (size_t)(m0 + row) * K + k0 + kc, ldsA);
      gload_lds16(Bt + (size_t)(n0 + row) * K + k0 + kc, ldsB);
    }
    __syncthreads();
#pragma unroll
    for (int kk = 0; kk < 2; ++kk) {
      bf16x8 af[4], bfr[4];
#pragma unroll
      for (int i = 0; i < 4; i++)
        af[i] = *reinterpret_cast<const bf16x8*>(As + (size_t)(wr * 64 + i * 16 + lo) * 64 + kk * 32 + g4 * 8);
#pragma unroll
      for (int j = 0; j < 4; j++)
        bfr[j] = *reinterpret_cast<const bf16x8*>(Bs + (size_t)(wc * 64 + j * 16 + lo) * 64 + kk * 32 + g4 * 8);
#pragma unroll
      for (int i = 0; i < 4; i++)
#pragma unroll
        for (int j = 0; j < 4; j++) acc[i][j] = MFMA16(af[i], bfr[j], acc[i][j]);
    }
    __syncthreads();
  }

#pragma unroll
  for (int i = 0; i < 4; i++) {
    int mrow = m0 + wr * 64 + i * 16 + g4 * 4;
#pragma unroll
    for (int j = 0; j < 4; j++) {
      int col = n0 + wc * 64 + j * 16 + lo;
      float bv = bias[col];
#pragma unroll
      for (int r = 0; r < 4; r++)
        Cout[(size_t)(mrow + r) * N + col] = acc[i][j][r] + bv;
    }
  }
}

// ---------------- causal flash attention v3: diagonal-paired, double-buffered ----------------
__launch_bounds__(256)
__global__ void attn_fwd_k(const HBF* __restrict__ Qb, const HBF* __restrict__ Kb,
                           const HBF* __restrict__ Vt, HBF* __restrict__ Ob) {
  __shared__ __align__(16) HBF Ks[2][64 * 64];
  __shared__ __align__(16) HBF Vs[2][64 * 64];
  __shared__ __align__(16) HBF pLds[4][2][16][72];
  const int tid = threadIdx.x;
  const int lane = tid & 63;
  const int w = tid >> 6;
  const int lo = lane & 15, g4 = lane >> 4;
  const int i = blockIdx.x, h = blockIdx.y, b = blockIdx.z;
  const int bh = b * 16 + h;
  const int baseT[2] = { i * 64 + w * 16, (31 - i) * 64 + w * 16 };
  const int nkv = 32 - i;

  const HBF* Qp = Qb + (size_t)bh * 2048 * 64;
  const HBF* Kp = Kb + (size_t)bh * 2048 * 64;
  const HBF* Vp = Vt + (size_t)bh * 64 * 2048;

  bf16x8 qf[2][2];
#pragma unroll
  for (int qt = 0; qt < 2; qt++)
#pragma unroll
    for (int ds = 0; ds < 2; ds++)
      qf[qt][ds] = *reinterpret_cast<const bf16x8*>(Qp + (size_t)(baseT[qt] + lo) * 64 + ds * 32 + g4 * 8);

  const f32x4 zero = {0.f, 0.f, 0.f, 0.f};
  f32x4 o[2][4];
  float m[2], l[2];
#pragma unroll
  for (int qt = 0; qt < 2; qt++) {
    m[qt] = -1e30f; l[qt] = 0.f;
#pragma unroll
    for (int j = 0; j < 4; j++) o[qt][j] = zero;
  }

  const int srow = (lane >> 3) & 7;
  const int sch = lane & 7;

  auto stage = [&](int kv0, int sb) {
#pragma unroll
    for (int c = 0; c < 2; c++) {
      int seg = w * 2 + c;
      int row = seg * 8 + srow;
      gload_lds16(Kp + (size_t)(kv0 + row) * 64 + ((sch ^ (row & 7)) * 8), &Ks[sb][seg * 512]);
      gload_lds16(Vp + (size_t)row * 2048 + kv0 + ((sch ^ (row & 7)) * 8), &Vs[sb][seg * 512]);
    }
  };

  stage(0, 0);
  __syncthreads();

  for (int t = 0; t < nkv; ++t) {
    const int kv0 = t * 64;
    const int sb = t & 1;
    if (t + 1 < nkv) stage(kv0 + 64, sb ^ 1);
    const bool doA = (t <= i);
    const bool diagT[2] = { t == i, t == nkv - 1 };

    f32x4 st[2][4];
#pragma unroll
    for (int kt = 0; kt < 4; kt++) {
      int krow = kt * 16 + lo;
      bf16x8 kf0 = *reinterpret_cast<const bf16x8*>(&Ks[sb][krow * 64 + ((g4 ^ (krow & 7)) * 8)]);
      bf16x8 kf1 = *reinterpret_cast<const bf16x8*>(&Ks[sb][krow * 64 + (((4 + g4) ^ (krow & 7)) * 8)]);
      f32x4 z = zero;
      z = MFMA16(kf0, qf[1][0], z);
      z = MFMA16(kf1, qf[1][1], z);
      st[1][kt] = z;
      if (doA) {
        f32x4 y = zero;
        y = MFMA16(kf0, qf[0][0], y);
        y = MFMA16(kf1, qf[0][1], y);
        st[0][kt] = y;
      }
    }

#pragma unroll
    for (int qt = 0; qt < 2; qt++) {
      if (qt == 0 && !doA) continue;
      const int q = baseT[qt] + lo;
      float pmax = -1e30f;
      if (diagT[qt]) {
#pragma unroll
        for (int kt = 0; kt < 4; kt++)
#pragma unroll
          for (int r = 0; r < 4; r++) {
            int key = kv0 + kt * 16 + g4 * 4 + r;
            float v = (key <= q) ? st[qt][kt][r] : -1e30f;
            st[qt][kt][r] = v;
            pmax = fmaxf(pmax, v);
          }
      } else {
#pragma unroll
        for (int kt = 0; kt < 4; kt++)
#pragma unroll
          for (int r = 0; r < 4; r++) pmax = fmaxf(pmax, st[qt][kt][r]);
      }
      pmax = fmaxf(pmax, __shfl_xor(pmax, 16));
      pmax = fmaxf(pmax, __shfl_xor(pmax, 32));
      if (__any(pmax > m[qt] + 11.5f)) {
        float mn = fmaxf(m[qt], pmax);
        float al = EXP2F(m[qt] - mn);
        m[qt] = mn;
        l[qt] *= al;
        float alr[4];
#pragma unroll
        for (int r = 0; r < 4; r++) alr[r] = __shfl(al, g4 * 4 + r);
#pragma unroll
        for (int j = 0; j < 4; j++)
#pragma unroll
          for (int r = 0; r < 4; r++) o[qt][j][r] *= alr[r];
      }
      float ps = 0.f;
#pragma unroll
      for (int kt = 0; kt < 4; kt++)
#pragma unroll
        for (int r = 0; r < 4; r++) {
          float p = EXP2F(st[qt][kt][r] - m[qt]);
          st[qt][kt][r] = p;
          ps += p;
        }
      ps += __shfl_xor(ps, 16);
      ps += __shfl_xor(ps, 32);
      l[qt] += ps;
#pragma unroll
      for (int kt = 0; kt < 4; kt++) {
        bf16x4 pk;
#pragma unroll
        for (int r = 0; r < 4; r++) pk[r] = (__bf16)st[qt][kt][r];
        *reinterpret_cast<bf16x4*>(&pLds[w][qt][lo][kt * 16 + g4 * 4]) = pk;
      }
    }

    bf16x8 paA[2], paB[2];
#pragma unroll
    for (int ks = 0; ks < 2; ks++) {
      paB[ks] = *reinterpret_cast<const bf16x8*>(&pLds[w][1][lo][ks * 32 + g4 * 8]);
      if (doA) paA[ks] = *reinterpret_cast<const bf16x8*>(&pLds[w][0][lo][ks * 32 + g4 * 8]);
    }
#pragma unroll
    for (int j = 0; j < 4; j++) {
      int vrow = j * 16 + lo;
#pragma unroll
      for (int ks = 0; ks < 2; ks++) {
        bf16x8 vb = *reinterpret_cast<const bf16x8*>(&Vs[sb][vrow * 64 + (((ks * 4 + g4) ^ (vrow & 7)) * 8)]);
        o[1][j] = MFMA16(paB[ks], vb, o[1][j]);
        if (doA) o[0][j] = MFMA16(paA[ks], vb, o[0][j]);
      }
    }
    __syncthreads();
  }

#pragma unroll
  for (int qt = 0; qt < 2; qt++) {
    float linv = 1.f / l[qt];
    float lr[4];
#pragma unroll
    for (int r = 0; r < 4; r++) lr[r] = __shfl(linv, g4 * 4 + r);
#pragma unroll
    for (int j = 0; j < 4; j++)
#pragma unroll
      for (int r = 0; r < 4; r++) {
        int q = baseT[qt] + g4 * 4 + r;
        Ob[(size_t)(b * 2048 + q) * 1024 + h * 64 + j * 16 + lo] =
            __float2bfloat16(o[qt][j][r] * lr[r]);
      }
  }
}

// ---------------- launch ----------------
extern "C" void kernel_launch(void* const* d_in, const int* in_sizes, int n_in,
                              void* d_out, int out_size, void* d_ws, size_t ws_size,
                              hipStream_t stream) {
  const float* x      = (const float*)d_in[0];
  const float* W_qkv  = (const float*)d_in[1];
  const float* b_qkv  = (const float*)d_in[2];
  const float* W_proj = (const float*)d_in[3];
  const float* b_proj = (const float*)d_in[4];
  float* out = (float*)d_out;

  const int B = 2, N = 2048, D = 1024, H = 16, DH = 64;
  const int M = B * N;  // 4096

  char* ws = (char*)d_ws;
  HBF* xb      = (HBF*)ws; ws += (size_t)M * D * 2;
  HBF* wqkv_t  = (HBF*)ws; ws += (size_t)H * 3 * DH * D * 2;
  HBF* wproj_t = (HBF*)ws; ws += (size_t)D * D * 2;
  HBF* Qb      = (HBF*)ws; ws += (size_t)B * H * N * DH * 2;
  HBF* Kb      = (HBF*)ws; ws += (size_t)B * H * N * DH * 2;
  HBF* Vt      = (HBF*)ws; ws += (size_t)B * H * DH * N * 2;
  HBF* Ob      = (HBF*)ws; ws += (size_t)M * D * 2;

  cast_f32_bf16_k<<<(M * D / 4 + 255) / 256, 256, 0, stream>>>(x, xb, M * D / 4);
  transpose_cast_k<float><<<dim3(192 / 32, D / 32, H), dim3(32, 8), 0, stream>>>(W_qkv, wqkv_t, D, 192);
  transpose_cast_k<float><<<dim3(D / 32, D / 32, 1), dim3(32, 8), 0, stream>>>(W_proj, wproj_t, D, D);
  // QKV GEMM (8-phase 256^2): scatter K, Q (pre-scaled), V^T
  gemm_qkv_8ph<<<192, 512, 0, stream>>>(xb, wqkv_t, b_qkv, Kb, Qb, Vt);
  attn_fwd_k<<<dim3(16, H, B), 256, 0, stream>>>(Qb, Kb, Vt, Ob);
  gemm_proj_k<<<dim3(D / 128, M / 128), 256, 0, stream>>>(Ob, wproj_t, M, D, D, b_proj, out);
}

// Round 7
// 138.587 us; speedup vs baseline: 2.4092x; 1.0553x over previous
//
#include <hip/hip_runtime.h>
#include <hip/hip_bf16.h>

typedef __hip_bfloat16 HBF;
typedef __bf16 bf16x8 __attribute__((ext_vector_type(8)));
typedef __bf16 bf16x4 __attribute__((ext_vector_type(4)));
typedef float f32x4 __attribute__((ext_vector_type(4)));
typedef float float4v __attribute__((ext_vector_type(4)));

__device__ __forceinline__ float toF(float x) { return x; }
__device__ __forceinline__ float toF(HBF x) { return __bfloat162float(x); }

#define MFMA16(a, b, c) __builtin_amdgcn_mfma_f32_16x16x32_bf16((a), (b), (c), 0, 0, 0)
#define EXP2F(x) __builtin_amdgcn_exp2f(x)
#define QSCALE 0.18033688011112042f
#define MEMFENCE asm volatile("" ::: "memory")

// async global->LDS, 16B per lane. LDS dest must be wave-uniform base; HW adds lane*16.
__device__ __forceinline__ void gload_lds16(const HBF* g, HBF* l) {
  __builtin_amdgcn_global_load_lds((const __attribute__((address_space(1))) void*)g,
                                   (__attribute__((address_space(3))) void*)l, 16, 0, 0);
}

// ---------------- elementwise cast f32 -> bf16 ----------------
struct bf4 { HBF v[4]; };
__global__ void cast_f32_bf16_k(const float* __restrict__ in, HBF* __restrict__ out, int n4) {
  int i = blockIdx.x * 256 + threadIdx.x;
  if (i >= n4) return;
  float4v a = reinterpret_cast<const float4v*>(in)[i];
  bf4 o;
  o.v[0] = __float2bfloat16(a.x); o.v[1] = __float2bfloat16(a.y);
  o.v[2] = __float2bfloat16(a.z); o.v[3] = __float2bfloat16(a.w);
  reinterpret_cast<bf4*>(out)[i] = o;
}

// ---------------- batched tiled transpose-cast ----------------
template <typename Tin>
__global__ void transpose_cast_k(const Tin* __restrict__ in, HBF* __restrict__ out, int R, int C) {
  __shared__ float tile[32][33];
  size_t base = (size_t)blockIdx.z * R * C;
  int r0 = blockIdx.y * 32, c0 = blockIdx.x * 32;
  int tx = threadIdx.x, ty = threadIdx.y;
#pragma unroll
  for (int i = ty; i < 32; i += 8)
    tile[i][tx] = toF(in[base + (size_t)(r0 + i) * C + c0 + tx]);
  __syncthreads();
#pragma unroll
  for (int i = ty; i < 32; i += 8)
    out[base + (size_t)(c0 + i) * R + r0 + tx] = __float2bfloat16(tile[tx][i]);
}

// ---------------- QKV GEMM: 256x256x64, 8-phase, swizzled LDS, counted vmcnt ----------------
__launch_bounds__(512, 2)
__global__ void gemm_qkv_8ph(const HBF* __restrict__ A, const HBF* __restrict__ Bt,
                             const float* __restrict__ bias,
                             HBF* __restrict__ Kout, HBF* __restrict__ Qout,
                             HBF* __restrict__ Vtout) {
  __shared__ __align__(16) HBF As[2][16384];
  __shared__ __align__(16) HBF Bs[2][16384];
  const int tid = threadIdx.x, lane = tid & 63, w = tid >> 6;
  const int lo = lane & 15, g4 = lane >> 4;
  const int wr = w >> 2, wc = w & 3;
  const int s = ((int)blockIdx.x & 7) * 24 + ((int)blockIdx.x >> 3);
  const int bx = s % 12, by = s / 12;
  const int m0 = by * 256, n0 = bx * 256;
  const int NT = 16;  // K=1024 / 64

  f32x4 acc[8][4];
#pragma unroll
  for (int i = 0; i < 8; i++)
#pragma unroll
    for (int j = 0; j < 4; j++) acc[i][j] = (f32x4){0.f, 0.f, 0.f, 0.f};
  bf16x8 af[8][2], bfr[4][2];

  const int rl0 = w * 8 + (lane >> 3);
  const int rl1 = 64 + rl0;
  const int kc0 = (lane & 7) ^ (rl0 & 7);
  const int kc1 = (lane & 7) ^ (rl1 & 7);

  auto stageH = [&](int j) {
    const int kt = j >> 2, ty = j & 3, bb = kt & 1, hf = ty & 1;
    HBF* base = (ty < 2) ? &As[bb][hf * 8192] : &Bs[bb][hf * 8192];
    const HBF* g = (ty < 2) ? A : Bt;
    const int r0g = ((ty < 2) ? m0 : n0) + hf * 128;
    gload_lds16(g + (size_t)(r0g + rl0) * 1024 + kt * 64 + kc0 * 8, base + w * 512);
    gload_lds16(g + (size_t)(r0g + rl1) * 1024 + kt * 64 + kc1 * 8, base + 4096 + w * 512);
  };
  auto ldA = [&](int bb, int mt, int ks) -> bf16x8 {
    int row = wr * 128 + mt * 16 + lo;
    return *reinterpret_cast<const bf16x8*>(&As[bb][row * 64 + ((ks * 32 + g4 * 8) ^ ((row & 7) * 8))]);
  };
  auto ldB = [&](int bb, int nt, int ks) -> bf16x8 {
    int row = wc * 64 + nt * 16 + lo;
    return *reinterpret_cast<const bf16x8*>(&Bs[bb][row * 64 + ((ks * 32 + g4 * 8) ^ ((row & 7) * 8))]);
  };

  stageH(0); stageH(1); stageH(2); stageH(3); stageH(4); stageH(5);
  asm volatile("s_waitcnt vmcnt(4)" ::: "memory");
  __builtin_amdgcn_s_barrier();
  MEMFENCE;

  for (int t = 0; t < NT; ++t) {
    const int bb = t & 1;
#pragma unroll
    for (int mt = 0; mt < 4; ++mt) { af[mt][0] = ldA(bb, mt, 0); af[mt][1] = ldA(bb, mt, 1); }
#pragma unroll
    for (int nt = 0; nt < 2; ++nt) { bfr[nt][0] = ldB(bb, nt, 0); bfr[nt][1] = ldB(bb, nt, 1); }
    { int j = 4 * t + 6; if (j < 4 * NT) stageH(j); }
    MEMFENCE; __builtin_amdgcn_s_barrier(); MEMFENCE;
    __builtin_amdgcn_s_setprio(1);
#pragma unroll
    for (int mt = 0; mt < 4; ++mt)
#pragma unroll
      for (int nt = 0; nt < 2; ++nt)
#pragma unroll
        for (int ks = 0; ks < 2; ++ks) acc[mt][nt] = MFMA16(af[mt][ks], bfr[nt][ks], acc[mt][nt]);
    __builtin_amdgcn_s_setprio(0);
    MEMFENCE; __builtin_amdgcn_s_barrier(); MEMFENCE;
#pragma unroll
    for (int mt = 4; mt < 8; ++mt) { af[mt][0] = ldA(bb, mt, 0); af[mt][1] = ldA(bb, mt, 1); }
#pragma unroll
    for (int nt = 2; nt < 4; ++nt) { bfr[nt][0] = ldB(bb, nt, 0); bfr[nt][1] = ldB(bb, nt, 1); }
    { int j = 4 * t + 7; if (j < 4 * NT) stageH(j); }
    MEMFENCE; __builtin_amdgcn_s_barrier(); MEMFENCE;
    __builtin_amdgcn_s_setprio(1);
#pragma unroll
    for (int mt = 4; mt < 8; ++mt)
#pragma unroll
      for (int nt = 0; nt < 2; ++nt)
#pragma unroll
        for (int ks = 0; ks < 2; ++ks) acc[mt][nt] = MFMA16(af[mt][ks], bfr[nt][ks], acc[mt][nt]);
    __builtin_amdgcn_s_setprio(0);
    MEMFENCE; __builtin_amdgcn_s_barrier(); MEMFENCE;
    { int j = 4 * t + 8; if (j < 4 * NT) stageH(j); }
    MEMFENCE; __builtin_amdgcn_s_barrier(); MEMFENCE;
    __builtin_amdgcn_s_setprio(1);
#pragma unroll
    for (int mt = 0; mt < 4; ++mt)
#pragma unroll
      for (int nt = 2; nt < 4; ++nt)
#pragma unroll
        for (int ks = 0; ks < 2; ++ks) acc[mt][nt] = MFMA16(af[mt][ks], bfr[nt][ks], acc[mt][nt]);
    __builtin_amdgcn_s_setprio(0);
    MEMFENCE; __builtin_amdgcn_s_barrier(); MEMFENCE;
    { int j = 4 * t + 9; if (j < 4 * NT) stageH(j); }
    MEMFENCE; __builtin_amdgcn_s_barrier(); MEMFENCE;
    __builtin_amdgcn_s_setprio(1);
#pragma unroll
    for (int mt = 4; mt < 8; ++mt)
#pragma unroll
      for (int nt = 2; nt < 4; ++nt)
#pragma unroll
        for (int ks = 0; ks < 2; ++ks) acc[mt][nt] = MFMA16(af[mt][ks], bfr[nt][ks], acc[mt][nt]);
    __builtin_amdgcn_s_setprio(0);
    asm volatile("s_waitcnt vmcnt(4)" ::: "memory");
    __builtin_amdgcn_s_barrier();
    MEMFENCE;
  }

#pragma unroll
  for (int mt = 0; mt < 8; ++mt) {
    int mrow = m0 + wr * 128 + mt * 16 + g4 * 4;
#pragma unroll
    for (int nt = 0; nt < 4; ++nt) {
      int col = n0 + wc * 64 + nt * 16 + lo;
      int h = col / 192, e = col % 192;
      float bv = bias[col];
#pragma unroll
      for (int r = 0; r < 4; ++r) {
        int mm = mrow + r;
        int b = mm >> 11, n = mm & 2047;
        float v = acc[mt][nt][r] + bv;
        size_t bh64 = (size_t)(b * 16 + h);
        if (e < 64)       Kout[(bh64 * 2048 + n) * 64 + e] = __float2bfloat16(v);
        else if (e < 128) Qout[(bh64 * 2048 + n) * 64 + e - 64] = __float2bfloat16(v * QSCALE);
        else              Vtout[(bh64 * 64 + (e - 128)) * 2048 + n] = __float2bfloat16(v);
      }
    }
  }
}

// ---------------- proj GEMM: m97-style 128x128x64, fp32 out + bias ----------------
__launch_bounds__(256)
__global__ void gemm_proj_k(const HBF* __restrict__ A, const HBF* __restrict__ Bt,
                            int M, int N, int K, const float* __restrict__ bias,
                            float* __restrict__ Cout) {
  __shared__ __align__(16) HBF As[128 * 64];
  __shared__ __align__(16) HBF Bs[128 * 64];
  const int tid = threadIdx.x;
  const int lane = tid & 63;
  const int w = tid >> 6;
  const int lo = lane & 15, g4 = lane >> 4;
  const int m0 = blockIdx.y * 128, n0 = blockIdx.x * 128;
  const int wr = w >> 1, wc = w & 1;

  const f32x4 zero = {0.f, 0.f, 0.f, 0.f};
  f32x4 acc[4][4];
#pragma unroll
  for (int i = 0; i < 4; i++)
#pragma unroll
    for (int j = 0; j < 4; j++) acc[i][j] = zero;

  for (int k0 = 0; k0 < K; k0 += 64) {
#pragma unroll
    for (int c = 0; c < 4; ++c) {
      int chunk = c * 256 + tid;
      int row = chunk >> 3, kc = (chunk & 7) * 8;
      HBF* ldsA = As + (size_t)(c * 256 + w * 64) * 8;
      HBF* ldsB = Bs + (size_t)(c * 256 + w * 64) * 8;
      gload_lds16(A + (size_t)(m0 + row) * K + k0 + kc, ldsA);
      gload_lds16(Bt + (size_t)(n0 + row) * K + k0 + kc, ldsB);
    }
    __syncthreads();
#pragma unroll
    for (int kk = 0; kk < 2; ++kk) {
      bf16x8 af[4], bfr[4];
#pragma unroll
      for (int i = 0; i < 4; i++)
        af[i] = *reinterpret_cast<const bf16x8*>(As + (size_t)(wr * 64 + i * 16 + lo) * 64 + kk * 32 + g4 * 8);
#pragma unroll
      for (int j = 0; j < 4; j++)
        bfr[j] = *reinterpret_cast<const bf16x8*>(Bs + (size_t)(wc * 64 + j * 16 + lo) * 64 + kk * 32 + g4 * 8);
#pragma unroll
      for (int i = 0; i < 4; i++)
#pragma unroll
        for (int j = 0; j < 4; j++) acc[i][j] = MFMA16(af[i], bfr[j], acc[i][j]);
    }
    __syncthreads();
  }

#pragma unroll
  for (int i = 0; i < 4; i++) {
    int mrow = m0 + wr * 64 + i * 16 + g4 * 4;
#pragma unroll
    for (int j = 0; j < 4; j++) {
      int col = n0 + wc * 64 + j * 16 + lo;
      float bv = bias[col];
#pragma unroll
      for (int r = 0; r < 4; r++)
        Cout[(size_t)(mrow + r) * N + col] = acc[i][j][r] + bv;
    }
  }
}

// ---------------- causal flash attention v4: single-tile blocks, XCD-clustered ----------------
// grid 1024 blocks (flat), 256 thr = 4 waves. Linear wg id -> xcd = lin&7; each XCD serves
// 4 (b,h) pairs; within an XCD, tiles dispatched longest-first (j = 31 - (c&31)).
// Block handles ONE 64-row q-tile j; wave w owns 16 rows. KVBLK=64 double-buffered.
// Swapped QK^T, lane-local online softmax in exp2 domain, defer-max, deferred l-reduce.
__launch_bounds__(256)
__global__ void attn_fwd_k(const HBF* __restrict__ Qb, const HBF* __restrict__ Kb,
                           const HBF* __restrict__ Vt, HBF* __restrict__ Ob) {
  __shared__ __align__(16) HBF Ks[2][64 * 64];
  __shared__ __align__(16) HBF Vs[2][64 * 64];
  __shared__ __align__(16) HBF pLds[4][16][72];
  const int tid = threadIdx.x;
  const int lane = tid & 63;
  const int w = tid >> 6;
  const int lo = lane & 15, g4 = lane >> 4;

  const int lin = blockIdx.x;
  const int xcd = lin & 7, c = lin >> 3;       // c in 0..127
  const int bh = xcd * 4 + (c >> 5);           // 4 (b,h) per XCD -> KV L2-resident
  const int j = 31 - (c & 31);                 // longest tiles dispatched first
  const int b = bh >> 4, h = bh & 15;
  const int qrow0 = j * 64 + w * 16;
  const int nkv = j + 1;

  const HBF* Qp = Qb + (size_t)bh * 2048 * 64;
  const HBF* Kp = Kb + (size_t)bh * 2048 * 64;
  const HBF* Vp = Vt + (size_t)bh * 64 * 2048;

  bf16x8 qf[2];
#pragma unroll
  for (int ds = 0; ds < 2; ds++)
    qf[ds] = *reinterpret_cast<const bf16x8*>(Qp + (size_t)(qrow0 + lo) * 64 + ds * 32 + g4 * 8);

  const f32x4 zero = {0.f, 0.f, 0.f, 0.f};
  f32x4 o[4];
  float m = -1e30f, l = 0.f;
#pragma unroll
  for (int j4 = 0; j4 < 4; j4++) o[j4] = zero;

  const int srow = (lane >> 3) & 7;
  const int sch = lane & 7;

  auto stage = [&](int kv0, int sb) {
#pragma unroll
    for (int cc = 0; cc < 2; cc++) {
      int seg = w * 2 + cc;
      int row = seg * 8 + srow;
      gload_lds16(Kp + (size_t)(kv0 + row) * 64 + ((sch ^ (row & 7)) * 8), &Ks[sb][seg * 512]);
      gload_lds16(Vp + (size_t)row * 2048 + kv0 + ((sch ^ (row & 7)) * 8), &Vs[sb][seg * 512]);
    }
  };

  stage(0, 0);
  __syncthreads();

  for (int t = 0; t < nkv; ++t) {
    const int kv0 = t * 64;
    const int sb = t & 1;
    if (t + 1 < nkv) stage(kv0 + 64, sb ^ 1);  // prefetch under compute

    // ---- S^T = K · Q^T ----
    f32x4 st[4];
#pragma unroll
    for (int kt = 0; kt < 4; kt++) {
      int krow = kt * 16 + lo;
      bf16x8 kf0 = *reinterpret_cast<const bf16x8*>(&Ks[sb][krow * 64 + ((g4 ^ (krow & 7)) * 8)]);
      bf16x8 kf1 = *reinterpret_cast<const bf16x8*>(&Ks[sb][krow * 64 + (((4 + g4) ^ (krow & 7)) * 8)]);
      f32x4 z = zero;
      z = MFMA16(kf0, qf[0], z);
      z = MFMA16(kf1, qf[1], z);
      st[kt] = z;
    }

    // ---- online softmax (lane owns q-col = qrow0 + lo) ----
    const int q = qrow0 + lo;
    float pmax = -1e30f;
    if (t == nkv - 1) {  // diagonal tile: mask
#pragma unroll
      for (int kt = 0; kt < 4; kt++)
#pragma unroll
        for (int r = 0; r < 4; r++) {
          int key = kv0 + kt * 16 + g4 * 4 + r;
          float v = (key <= q) ? st[kt][r] : -1e30f;
          st[kt][r] = v;
          pmax = fmaxf(pmax, v);
        }
    } else {
#pragma unroll
      for (int kt = 0; kt < 4; kt++)
#pragma unroll
        for (int r = 0; r < 4; r++) pmax = fmaxf(pmax, st[kt][r]);
    }
    pmax = fmaxf(pmax, __shfl_xor(pmax, 16));
    pmax = fmaxf(pmax, __shfl_xor(pmax, 32));
    if (__any(pmax > m + 11.5f)) {  // defer-max
      float mn = fmaxf(m, pmax);
      float al = EXP2F(m - mn);
      m = mn;
      l *= al;
      float alr[4];
#pragma unroll
      for (int r = 0; r < 4; r++) alr[r] = __shfl(al, g4 * 4 + r);
#pragma unroll
      for (int j4 = 0; j4 < 4; j4++)
#pragma unroll
        for (int r = 0; r < 4; r++) o[j4][r] *= alr[r];
    }
#pragma unroll
    for (int kt = 0; kt < 4; kt++)
#pragma unroll
      for (int r = 0; r < 4; r++) {
        float p = EXP2F(st[kt][r] - m);
        st[kt][r] = p;
        l += p;  // lane-partial; cross-lane reduce deferred to epilogue
      }
#pragma unroll
    for (int kt = 0; kt < 4; kt++) {
      bf16x4 pk;
#pragma unroll
      for (int r = 0; r < 4; r++) pk[r] = (__bf16)st[kt][r];
      *reinterpret_cast<bf16x4*>(&pLds[w][lo][kt * 16 + g4 * 4]) = pk;
    }
    asm volatile("s_waitcnt lgkmcnt(0)" ::: "memory");
    __builtin_amdgcn_sched_barrier(0);

    // ---- PV ----
    bf16x8 pa[2];
#pragma unroll
    for (int ks = 0; ks < 2; ks++)
      pa[ks] = *reinterpret_cast<const bf16x8*>(&pLds[w][lo][ks * 32 + g4 * 8]);
#pragma unroll
    for (int j4 = 0; j4 < 4; j4++) {
      int vrow = j4 * 16 + lo;
#pragma unroll
      for (int ks = 0; ks < 2; ks++) {
        bf16x8 vb = *reinterpret_cast<const bf16x8*>(&Vs[sb][vrow * 64 + (((ks * 4 + g4) ^ (vrow & 7)) * 8)]);
        o[j4] = MFMA16(pa[ks], vb, o[j4]);
      }
    }
    __syncthreads();  // drains prefetch (full compute phase elapsed) + protects LDS reuse
  }

  // ---- epilogue: reduce l across the 4 q-sharing lanes, then write ----
  l += __shfl_xor(l, 16);
  l += __shfl_xor(l, 32);
  float linv = 1.f / l;
  float lr[4];
#pragma unroll
  for (int r = 0; r < 4; r++) lr[r] = __shfl(linv, g4 * 4 + r);
#pragma unroll
  for (int j4 = 0; j4 < 4; j4++)
#pragma unroll
    for (int r = 0; r < 4; r++) {
      int q = qrow0 + g4 * 4 + r;
      Ob[(size_t)(b * 2048 + q) * 1024 + h * 64 + j4 * 16 + lo] =
          __float2bfloat16(o[j4][r] * lr[r]);
    }
}

// ---------------- launch ----------------
extern "C" void kernel_launch(void* const* d_in, const int* in_sizes, int n_in,
                              void* d_out, int out_size, void* d_ws, size_t ws_size,
                              hipStream_t stream) {
  const float* x      = (const float*)d_in[0];
  const float* W_qkv  = (const float*)d_in[1];
  const float* b_qkv  = (const float*)d_in[2];
  const float* W_proj = (const float*)d_in[3];
  const float* b_proj = (const float*)d_in[4];
  float* out = (float*)d_out;

  const int B = 2, N = 2048, D = 1024, H = 16, DH = 64;
  const int M = B * N;  // 4096

  char* ws = (char*)d_ws;
  HBF* xb      = (HBF*)ws; ws += (size_t)M * D * 2;
  HBF* wqkv_t  = (HBF*)ws; ws += (size_t)H * 3 * DH * D * 2;
  HBF* wproj_t = (HBF*)ws; ws += (size_t)D * D * 2;
  HBF* Qb      = (HBF*)ws; ws += (size_t)B * H * N * DH * 2;
  HBF* Kb      = (HBF*)ws; ws += (size_t)B * H * N * DH * 2;
  HBF* Vt      = (HBF*)ws; ws += (size_t)B * H * DH * N * 2;
  HBF* Ob      = (HBF*)ws; ws += (size_t)M * D * 2;

  cast_f32_bf16_k<<<(M * D / 4 + 255) / 256, 256, 0, stream>>>(x, xb, M * D / 4);
  transpose_cast_k<float><<<dim3(192 / 32, D / 32, H), dim3(32, 8), 0, stream>>>(W_qkv, wqkv_t, D, 192);
  transpose_cast_k<float><<<dim3(D / 32, D / 32, 1), dim3(32, 8), 0, stream>>>(W_proj, wproj_t, D, D);
  gemm_qkv_8ph<<<192, 512, 0, stream>>>(xb, wqkv_t, b_qkv, Kb, Qb, Vt);
  attn_fwd_k<<<1024, 256, 0, stream>>>(Qb, Kb, Vt, Ob);
  gemm_proj_k<<<dim3(D / 128, M / 128), 256, 0, stream>>>(Ob, wproj_t, M, D, D, b_proj, out);
}